// Round 12
// baseline (144.166 us; speedup 1.0000x reference)
//
#include <hip/hip_runtime.h>

#define NN 100000
#define NE 3200000
#define DIN 128
#define DHID 16
#define DOUT 2
#define NBUCK 391            // ceil(NN/256) buckets of 256 dst nodes
#define EPT 16               // edges per thread in hist/fill
#define BHT 1024             // threads in hist/fill blocks
#define EPB (BHT * EPT)      // 16384 edges per block
#define NBB ((NE + EPB - 1) / EPB)  // 196
#define MMB 391              // mm1-role blocks (256 nodes each)
#define P2CAP 10240          // LDS edge buffer in pass2 (40 KB); avg bucket 8184

// round-to-nearest-even f32 -> bf16 (bits)
__device__ __forceinline__ unsigned f2bf(float f) {
    unsigned u = __float_as_uint(f);
    return (u + 0x7FFFu + ((u >> 16) & 1u)) >> 16;
}
__device__ __forceinline__ float bflo(unsigned a) { return __uint_as_float(a << 16); }
__device__ __forceinline__ float bfhi(unsigned a) { return __uint_as_float(a & 0xFFFF0000u); }

// ---------------- bucket count zero ----------------
__global__ __launch_bounds__(512) void k_zero_b(int* __restrict__ bcount) {
    int t = threadIdx.x;
    if (t < NBUCK) bcount[t] = 0;
}

// ---------------- coarse bucket histogram (dst >> 8) ----------------
__global__ __launch_bounds__(BHT) void k_bhist(const int* __restrict__ dst,
                                               int* __restrict__ bcount) {
    __shared__ int h[NBUCK];
    int t = threadIdx.x;
    for (int i = t; i < NBUCK; i += BHT) h[i] = 0;
    __syncthreads();
    long long base = (long long)blockIdx.x * EPB;
#pragma unroll
    for (int k = 0; k < EPT; ++k) {
        long long e = base + (long long)k * BHT + t;
        if (e < NE) atomicAdd(&h[((unsigned)dst[e]) >> 8], 1);
    }
    __syncthreads();
    for (int i = t; i < NBUCK; i += BHT) {
        int c = h[i];
        if (c) atomicAdd(&bcount[i], c);
    }
}

// ---------------- scan 391 bucket counts ----------------
__global__ __launch_bounds__(512) void k_bscan(const int* __restrict__ bcount,
                                               int* __restrict__ bstart,
                                               int* __restrict__ bcursor) {
    __shared__ int sc[512];
    int t = threadIdx.x;
    int c = (t < NBUCK) ? bcount[t] : 0;
    sc[t] = c;
    __syncthreads();
    for (int off = 1; off < 512; off <<= 1) {
        int v = sc[t];
        int add = (t >= off) ? sc[t - off] : 0;
        __syncthreads();
        sc[t] = v + add;
        __syncthreads();
    }
    int excl = sc[t] - c;
    if (t <= NBUCK) bstart[t] = excl;  // bstart[NBUCK] == NE
    if (t < NBUCK) bcursor[t] = excl;
}

// ---------------- merged: bfill (blocks 0..NBB-1) + mm1 (blocks NBB..) -----
// bfill role: bucket the edges, packed = (dstLow<<24)|src.
// mm1 role: h1 = x @ W1 (UNSCALED; dinv applied at gather time), bf16x2-packed
// into g1b. Roles are block-uniform; mm1 depends only on x/W1, so its ~24 us
// hides under bfill's memory/atomic-bound blocks (196 < 256 CUs).
__global__ __launch_bounds__(BHT) void k_bfill_mm1(const int* __restrict__ src,
                                                   const int* __restrict__ dst,
                                                   int* __restrict__ bcursor,
                                                   unsigned* __restrict__ packed,
                                                   const float* __restrict__ x,
                                                   const float* __restrict__ W1,
                                                   unsigned* __restrict__ g1b) {
    __shared__ float Ws[DIN * DHID];     // 8 KB; mm1 role
    __shared__ int h[NBUCK];             // bfill role: hist then cursor
    __shared__ int hbase[NBUCK];
    int t = threadIdx.x;
    if (blockIdx.x >= NBB) {
        // ---- mm1 role: 256 nodes/block, 4 lanes/node (R4-proven DPP) ----
        for (int i = t; i < DIN * DHID; i += BHT) Ws[i] = W1[i];
        __syncthreads();
        int v = (blockIdx.x - NBB) * 256 + (t >> 2);
        int q = t & 3;
        if (v >= NN) return;
        float4 xq[8];
        const float4* xr = (const float4*)(x + (size_t)v * DIN + q * 32);
#pragma unroll
        for (int i = 0; i < 8; ++i) xq[i] = xr[i];
        const float* xs = (const float*)xq;
        float acc0 = 0.f, acc1 = 0.f, acc2 = 0.f, acc3 = 0.f;
#define QSTEP(QQ, CTRL)                                                          \
    _Pragma("unroll")                                                            \
    for (int k = 0; k < 32; ++k) {                                               \
        float xv = __int_as_float(                                               \
            __builtin_amdgcn_mov_dpp(__float_as_int(xs[k]), CTRL, 0xF, 0xF, false)); \
        const float4 w = *(const float4*)&Ws[(QQ * 32 + k) * DHID + q * 4];      \
        acc0 += xv * w.x; acc1 += xv * w.y; acc2 += xv * w.z; acc3 += xv * w.w;  \
    }
        QSTEP(0, 0x00)
        QSTEP(1, 0x55)
        QSTEP(2, 0xAA)
        QSTEP(3, 0xFF)
#undef QSTEP
        unsigned u0 = f2bf(acc0) | (f2bf(acc1) << 16);
        unsigned u1 = f2bf(acc2) | (f2bf(acc3) << 16);
        ((uint2*)(g1b + (size_t)v * 8))[q] = make_uint2(u0, u1);
        return;
    }
    // ---- bfill role (R10-verbatim) ----
    for (int i = t; i < NBUCK; i += BHT) h[i] = 0;
    __syncthreads();
    long long base = (long long)blockIdx.x * EPB;
    int ed[EPT], es[EPT];
#pragma unroll
    for (int k = 0; k < EPT; ++k) {
        long long e = base + (long long)k * BHT + t;
        if (e < NE) {
            ed[k] = dst[e];
            es[k] = src[e];
            atomicAdd(&h[((unsigned)ed[k]) >> 8], 1);
        } else {
            ed[k] = -1;
            es[k] = 0;
        }
    }
    __syncthreads();
    for (int i = t; i < NBUCK; i += BHT) {
        int c = h[i];
        hbase[i] = c ? atomicAdd(&bcursor[i], c) : 0;
    }
    __syncthreads();
    for (int i = t; i < NBUCK; i += BHT) h[i] = 0;
    __syncthreads();
#pragma unroll
    for (int k = 0; k < EPT; ++k) {
        if (ed[k] >= 0) {
            unsigned d = (unsigned)ed[k];
            int b = d >> 8;
            int off = atomicAdd(&h[b], 1);
            packed[hbase[b] + off] = ((d & 255u) << 24) | (unsigned)es[k];
        }
    }
}

// ---------------- per-bucket exact sort -> rowstart, dinv, esrc ----------------
__global__ __launch_bounds__(256) void k_pass2(const int* __restrict__ bstart,
                                               const unsigned* __restrict__ packed,
                                               int* __restrict__ rowstart,
                                               float* __restrict__ dinv,
                                               int* __restrict__ esrc) {
    __shared__ unsigned ebuf[P2CAP];  // 40 KB
    __shared__ int h[256], sc[256], cur[256];
    int b = blockIdx.x;
    int t = threadIdx.x;
    int dst0 = b << 8;
    int ebeg = bstart[b];
    int eend = bstart[b + 1];
    int n = eend - ebeg;
    bool fits = (n <= P2CAP);
    h[t] = 0;
    __syncthreads();
    if (fits) {
        for (int i = t; i < n; i += 256) {
            unsigned pk = packed[ebeg + i];
            ebuf[i] = pk;
            atomicAdd(&h[pk >> 24], 1);
        }
    } else {
        for (int i = t; i < n; i += 256)
            atomicAdd(&h[packed[ebeg + i] >> 24], 1);
    }
    __syncthreads();
    int c = h[t];
    sc[t] = c;
    __syncthreads();
    for (int off = 1; off < 256; off <<= 1) {
        int v = sc[t];
        int add = (t >= off) ? sc[t - off] : 0;
        __syncthreads();
        sc[t] = v + add;
        __syncthreads();
    }
    int gpos = ebeg + sc[t] - c;
    int v = dst0 + t;
    if (v < NN) {
        rowstart[v] = gpos;
        dinv[v] = rsqrtf((float)(c + 1));
    }
    cur[t] = gpos;
    if (b == 0 && t == 0) rowstart[NN] = NE;
    __syncthreads();
    if (fits) {
        for (int i = t; i < n; i += 256) {
            unsigned pk = ebuf[i];
            int pos = atomicAdd(&cur[pk >> 24], 1);
            esrc[pos] = (int)(pk & 0xFFFFFFu);
        }
    } else {
        for (int i = t; i < n; i += 256) {
            unsigned pk = packed[ebeg + i];
            int pos = atomicAdd(&cur[pk >> 24], 1);
            esrc[pos] = (int)(pk & 0xFFFFFFu);
        }
    }
}

// ---------------- layer 1 gather + fused layer-2 transform ----------------
// 8 lanes/node; lane j owns channels 2j,2j+1. h1 is UNSCALED: apply dinv[u]
// per edge (broadcast 4B L2 load) and dinv[v] on self-loop + epilogue.
__global__ __launch_bounds__(256) void k_gather1mm2(const int* __restrict__ rowstart,
                                                    const int* __restrict__ esrc,
                                                    const float* __restrict__ dinv,
                                                    const unsigned* __restrict__ G,
                                                    const float* __restrict__ b1,
                                                    const float* __restrict__ W2,
                                                    float* __restrict__ g2) {
    int t = blockIdx.x * 256 + threadIdx.x;
    int v = t >> 3;
    int j = t & 7;
    if (v >= NN) return;
    int beg = rowstart[v];
    int end = rowstart[v + 1];
    float dvv = dinv[v];
    unsigned a = G[(v << 3) + j];  // self loop: dinv[v]*h1[v]
    float c0 = dvv * bflo(a), c1 = dvv * bfhi(a);
    int p = beg;
    int n4 = beg + ((end - beg) & ~3);
    for (; p < n4; p += 4) {
        int u0 = esrc[p], u1 = esrc[p + 1], u2 = esrc[p + 2], u3 = esrc[p + 3];
        float d0 = dinv[u0], d1 = dinv[u1], d2 = dinv[u2], d3 = dinv[u3];
        unsigned b0 = G[(u0 << 3) + j];
        unsigned b1w = G[(u1 << 3) + j];
        unsigned b2w = G[(u2 << 3) + j];
        unsigned b3w = G[(u3 << 3) + j];
        c0 = fmaf(d0, bflo(b0), fmaf(d1, bflo(b1w), fmaf(d2, bflo(b2w), fmaf(d3, bflo(b3w), c0))));
        c1 = fmaf(d0, bfhi(b0), fmaf(d1, bfhi(b1w), fmaf(d2, bfhi(b2w), fmaf(d3, bfhi(b3w), c1))));
    }
    for (; p < end; ++p) {
        int u = esrc[p];
        float d = dinv[u];
        unsigned b = G[(u << 3) + j];
        c0 = fmaf(d, bflo(b), c0);
        c1 = fmaf(d, bfhi(b), c1);
    }
    // fused mm2: relu(out1 + b1) @ W2, partial over this lane's 2 channels
    float o0 = fmaxf(c0 * dvv + b1[2 * j], 0.f);
    float o1 = fmaxf(c1 * dvv + b1[2 * j + 1], 0.f);
    float p0 = o0 * W2[(2 * j) * 2 + 0] + o1 * W2[(2 * j + 1) * 2 + 0];
    float p1 = o0 * W2[(2 * j) * 2 + 1] + o1 * W2[(2 * j + 1) * 2 + 1];
    p0 += __shfl_xor(p0, 1); p0 += __shfl_xor(p0, 2); p0 += __shfl_xor(p0, 4);
    p1 += __shfl_xor(p1, 1); p1 += __shfl_xor(p1, 2); p1 += __shfl_xor(p1, 4);
    if (j == 0) {
        float2 w = make_float2(p0 * dvv, p1 * dvv);
        *(float2*)(g2 + (size_t)v * 2) = w;
    }
}

// ---------------- layer 2 gather: 8 lanes/node = 4 edge-slots x 2 ch -------
__global__ __launch_bounds__(256) void k_gather2(const int* __restrict__ rowstart,
                                                 const int* __restrict__ esrc,
                                                 const float* __restrict__ dinv,
                                                 const float* __restrict__ g2,
                                                 const float* __restrict__ b2,
                                                 float* __restrict__ out) {
    int t = blockIdx.x * 256 + threadIdx.x;
    int v = t >> 3;
    if (v >= NN) return;
    int lane = t & 7;
    int ch = lane & 1;
    int slot = lane >> 1;
    int beg = rowstart[v];
    int end = rowstart[v + 1];
    float acc = 0.0f;
    for (int p = beg + slot; p < end; p += 4)
        acc += g2[(esrc[p] << 1) + ch];
    acc += __shfl_xor(acc, 2);
    acc += __shfl_xor(acc, 4);  // all slots summed
    float o = (acc + g2[(v << 1) + ch]) * dinv[v] + b2[ch];
    float other = __shfl_xor(o, 1);
    float m = fmaxf(o, other);
    float lse = m + logf(expf(o - m) + expf(other - m));
    if (slot == 0) out[(v << 1) + ch] = o - lse;
}

extern "C" void kernel_launch(void* const* d_in, const int* in_sizes, int n_in,
                              void* d_out, int out_size, void* d_ws, size_t ws_size,
                              hipStream_t stream) {
    const float* x  = (const float*)d_in[0];
    const float* W1 = (const float*)d_in[1];
    const float* b1 = (const float*)d_in[2];
    const float* W2 = (const float*)d_in[3];
    const float* b2 = (const float*)d_in[4];
    const int* ei   = (const int*)d_in[5];
    const int* src = ei;
    const int* dst = ei + NE;

    // workspace (4B elems). g1b NO LONGER aliases packed: they are written
    // concurrently by the merged k_bfill_mm1 (race otherwise).
    int* ws       = (int*)d_ws;
    int* bcount   = ws;                    // 400
    int* bstart   = ws + 400;              // 400 (uses NBUCK+1)
    int* bcursor  = ws + 800;              // 400
    int* rowstart = ws + 1200;             // NN+16
    float* dinv   = (float*)(ws + 1200 + NN + 16);    // NN
    int* esrc     = ws + 1200 + 2 * NN + 16;          // NE
    unsigned* packed = (unsigned*)(esrc + NE);        // NE
    unsigned* g1b = packed + NE;           // 8*NN (own region, 16B-aligned)
    float* g2     = (float*)(g1b + 8 * NN); // 2*NN

    float* out = (float*)d_out;

    k_zero_b<<<1, 512, 0, stream>>>(bcount);
    k_bhist<<<NBB, BHT, 0, stream>>>(dst, bcount);
    k_bscan<<<1, 512, 0, stream>>>(bcount, bstart, bcursor);
    k_bfill_mm1<<<NBB + MMB, BHT, 0, stream>>>(src, dst, bcursor, packed, x, W1, g1b);
    k_pass2<<<NBUCK, 256, 0, stream>>>(bstart, packed, rowstart, dinv, esrc);
    k_gather1mm2<<<(NN * 8 + 255) / 256, 256, 0, stream>>>(rowstart, esrc, dinv, g1b, b1, W2, g2);
    k_gather2<<<(NN * 8 + 255) / 256, 256, 0, stream>>>(rowstart, esrc, dinv, g2, b2, out);
}